// Round 8
// baseline (71.647 us; speedup 1.0000x reference)
//
#include <hip/hip_runtime.h>

typedef _Float16 h8     __attribute__((ext_vector_type(8)));
typedef float    f32x16 __attribute__((ext_vector_type(16)));

#define BB      16
#define NPTS    4096
#define WAVES   4                       // waves per block
#define RPW     64                      // rows per wave = 2 row-blocks of 32
#define RPB     (WAVES * RPW)           // 256 rows per block
#define CSPLIT  2                       // column split across blocks
#define COLS    (NPTS / CSPLIT)         // 2048 cols per block
#define CHUNK   256                     // cols staged per LDS chunk
#define NCHUNK  (COLS / CHUNK)          // 8
#define TPB     (WAVES * 64)            // 256

__global__ __launch_bounds__(256) void chamfer_init_out(float* __restrict__ out) {
    int i = blockIdx.x * 256 + threadIdx.x;
    out[i] = 3.0e38f;
}

// d2(a,b) = s1 + s2 - 2 a.b via K=13 fp16-split dot (proven R6/R7, absmax 1e-3):
//  A half0 = [xh,yh,zh, xh,yh,zh, xl,yl]   A half1 = [zl, s1h,s1l, 1,1, 0,0,0]
//  B half0 = [-2xh,-2yh,-2zh, -2xl,-2yl,-2zl, -2xh,-2yh]
//  B half1 = [-2zh, 1,1, s2h,s2l, 0,0,0]
// LDS: tile t (32 cols), k-half hf, col c: half-off = t*512 + hf*256 + (c&31)*8
//  -> wave ds_read_b128 is linear 1024B, conflict-free (verified R7: conflicts gone).
__global__ __launch_bounds__(TPB) void chamfer_mfma(
    const float* __restrict__ xyz1,
    const float* __restrict__ xyz2,
    float* __restrict__ out)
{
    __shared__ __align__(16) _Float16 sb[2][CHUNK * 16];

    const int tid  = threadIdx.x;
    const int lane = tid & 63;
    const int wv   = tid >> 6;
    const int rb   = blockIdx.x;       // row-block 0..15
    const int b    = blockIdx.y;       // batch
    const int z    = blockIdx.z;       // dir + col-split
    const int dir  = z & 1;
    const int csp  = z >> 1;           // 0..CSPLIT-1

    const float* qbase = (dir == 0 ? xyz1 : xyz2) + b * NPTS * 3;
    const float* dbase = (dir == 0 ? xyz2 : xyz1) + b * NPTS * 3 + csp * COLS * 3;

    // ---- two A fragments per wave (row-blocks of 32) ----
    h8 af[2];
#pragma unroll
    for (int rbi = 0; rbi < 2; ++rbi) {
        const int row = rb * RPB + wv * RPW + rbi * 32 + (lane & 31);
        float x = qbase[row * 3 + 0], y = qbase[row * 3 + 1], z2 = qbase[row * 3 + 2];
        float s = fmaf(x, x, fmaf(y, y, z2 * z2));
        _Float16 xh = (_Float16)x, yh = (_Float16)y, zh = (_Float16)z2;
        _Float16 xl = (_Float16)(x - (float)xh);
        _Float16 yl = (_Float16)(y - (float)yh);
        _Float16 zl = (_Float16)(z2 - (float)zh);
        _Float16 sh = (_Float16)s;
        _Float16 sl = (_Float16)(s - (float)sh);
        _Float16 one = (_Float16)1.0f, zero = (_Float16)0.0f;
        af[rbi] = (lane < 32) ? h8{xh, yh, zh, xh, yh, zh, xl, yl}
                              : h8{zl, sh, sl, one, one, zero, zero, zero};
    }

    const f32x16 Z = {};
    float rm[2][16];
#pragma unroll
    for (int rbi = 0; rbi < 2; ++rbi)
#pragma unroll
        for (int r = 0; r < 16; ++r) rm[rbi][r] = 3.0e38f;

    const int loff = ((lane >> 5) << 8) + (lane & 31) * 8;   // halfs

    // ---- staging: one col per thread per chunk (CHUNK == TPB) ----
    float vx, vy, vz;
    auto stage_load = [&](int ch) {
        const float* p = dbase + (ch * CHUNK + tid) * 3;
        vx = p[0]; vy = p[1]; vz = p[2];
    };
    auto stage_write = [&](int buf) {
        float s = fmaf(vx, vx, fmaf(vy, vy, vz * vz));
        _Float16 xh = (_Float16)vx, yh = (_Float16)vy, zh = (_Float16)vz;
        _Float16 m2xh = (_Float16)(-2.0f) * xh;
        _Float16 m2yh = (_Float16)(-2.0f) * yh;
        _Float16 m2zh = (_Float16)(-2.0f) * zh;
        _Float16 m2xl = (_Float16)(-2.0f * (vx - (float)xh));
        _Float16 m2yl = (_Float16)(-2.0f * (vy - (float)yh));
        _Float16 m2zl = (_Float16)(-2.0f * (vz - (float)zh));
        _Float16 sh = (_Float16)s;
        _Float16 sl = (_Float16)(s - (float)sh);
        _Float16 one = (_Float16)1.0f, zero = (_Float16)0.0f;
        int off = (tid >> 5) * 512 + (tid & 31) * 8;
        *(h8*)&sb[buf][off]       = h8{m2xh, m2yh, m2zh, m2xl, m2yl, m2zl, m2xh, m2yh};
        *(h8*)&sb[buf][off + 256] = h8{m2zh, one, one, sh, sl, zero, zero, zero};
    };

    auto sweep = [&](int buf) {
        const _Float16* base = &sb[buf][0];
#pragma unroll
        for (int t = 0; t < CHUNK / 32; t += 2) {
            h8 b0 = *(const h8*)(base + t * 512 + loff);
            h8 b1 = *(const h8*)(base + (t + 1) * 512 + loff);
#pragma unroll
            for (int rbi = 0; rbi < 2; ++rbi) {
                f32x16 a0 = __builtin_amdgcn_mfma_f32_32x32x16_f16(af[rbi], b0, Z, 0, 0, 0);
                f32x16 a1 = __builtin_amdgcn_mfma_f32_32x32x16_f16(af[rbi], b1, Z, 0, 0, 0);
#pragma unroll
                for (int r = 0; r < 16; ++r)
                    rm[rbi][r] = fminf(fminf(a0[r], a1[r]), rm[rbi][r]);  // v_min3_f32
            }
        }
    };

    stage_load(0);
    stage_write(0);
    __syncthreads();
#pragma unroll 1
    for (int ch = 0; ch < NCHUNK; ++ch) {
        int buf = ch & 1;
        if (ch + 1 < NCHUNK) stage_load(ch + 1);
        sweep(buf);
        if (ch + 1 < NCHUNK) stage_write(buf ^ 1);
        __syncthreads();
    }

    // ---- reduce over 32 col-lanes (butterfly within each half) ----
#pragma unroll
    for (int rbi = 0; rbi < 2; ++rbi)
#pragma unroll
        for (int r = 0; r < 16; ++r) {
            float m = rm[rbi][r];
            m = fminf(m, __shfl_xor(m, 1));
            m = fminf(m, __shfl_xor(m, 2));
            m = fminf(m, __shfl_xor(m, 4));
            m = fminf(m, __shfl_xor(m, 8));
            m = fminf(m, __shfl_xor(m, 16));
            rm[rbi][r] = m;
        }
    // ---- combine across col-splits via int atomicMin (values >= 0) ----
    if ((lane & 31) == 0) {
        const int half = lane >> 5;
        int* o = (int*)out + dir * (BB * NPTS) + b * NPTS + rb * RPB + wv * RPW;
#pragma unroll
        for (int rbi = 0; rbi < 2; ++rbi)
#pragma unroll
            for (int r = 0; r < 16; ++r) {
                int rr = (r & 3) + 8 * (r >> 2) + 4 * half;   // C/D row map (m74/m101)
                float val = fmaxf(rm[rbi][r], 0.0f);
                atomicMin(o + rbi * 32 + rr, __float_as_int(val));
            }
    }
}

extern "C" void kernel_launch(void* const* d_in, const int* in_sizes, int n_in,
                              void* d_out, int out_size, void* d_ws, size_t ws_size,
                              hipStream_t stream) {
    const float* xyz1 = (const float*)d_in[0];
    const float* xyz2 = (const float*)d_in[1];
    float* out = (float*)d_out;

    // init output to +big (harness poisons d_out; must rewrite every call)
    hipLaunchKernelGGL(chamfer_init_out, dim3(2 * BB * NPTS / 256), dim3(256), 0, stream, out);

    dim3 grid(NPTS / RPB, BB, 2 * CSPLIT);   // 16 x 16 x 4 = 1024 blocks
    hipLaunchKernelGGL(chamfer_mfma, grid, dim3(TPB), 0, stream, xyz1, xyz2, out);
}

// Round 9
// 34.065 us; speedup vs baseline: 2.1032x; 2.1032x over previous
//
#include <hip/hip_runtime.h>

typedef _Float16 h8     __attribute__((ext_vector_type(8)));
typedef float    f32x16 __attribute__((ext_vector_type(16)));

#define BB      16
#define NPTS    4096
#define WAVES   4                       // waves per block
#define RPW     64                      // rows per wave = 2 row-blocks of 32
#define RPB     (WAVES * RPW)           // 256 rows per block
#define CSPLIT  2                       // column split across blocks
#define COLS    (NPTS / CSPLIT)         // 2048 cols per block
#define CHUNK   256                     // cols staged per LDS chunk
#define NCHUNK  (COLS / CHUNK)          // 8
#define TPB     (WAVES * 64)            // 256

__global__ __launch_bounds__(256) void chamfer_init_out(float* __restrict__ out) {
    int i = blockIdx.x * 256 + threadIdx.x;
    out[i] = 3.0e38f;
}

// d2(a,b) = s1 + s2 - 2 a.b via K=13 fp16-split dot (proven R6-R8, absmax 1e-3):
//  A half0 = [xh,yh,zh, xh,yh,zh, xl,yl]   A half1 = [zl, s1h,s1l, 1,1, 0,0,0]
//  B half0 = [-2xh,-2yh,-2zh, -2xl,-2yl,-2zl, -2xh,-2yh]
//  B half1 = [-2zh, 1,1, s2h,s2l, 0,0,0]
// LDS: tile t (32 cols), k-half hf, col c: half-off = t*512 + hf*256 + (c&31)*8
//  -> wave ds_read_b128 linear 1024B, conflict-free (verified R7/R8: conflicts ~0).
// VGPR discipline (R8 lesson): full unroll put ~32 f32x16 in flight -> VGPR=256
// cap + scratch spill (FETCH 6.3MB, WRITE 5.6MB). unroll 1 + launch_bounds(,4)
// keeps live set ~115 so 4 waves/SIMD fit.
__global__ __launch_bounds__(TPB, 4) void chamfer_mfma(
    const float* __restrict__ xyz1,
    const float* __restrict__ xyz2,
    float* __restrict__ out)
{
    __shared__ __align__(16) _Float16 sb[2][CHUNK * 16];

    const int tid  = threadIdx.x;
    const int lane = tid & 63;
    const int wv   = tid >> 6;
    const int rb   = blockIdx.x;       // row-block 0..15
    const int b    = blockIdx.y;       // batch
    const int z    = blockIdx.z;       // dir + col-split
    const int dir  = z & 1;
    const int csp  = z >> 1;           // 0..CSPLIT-1

    const float* qbase = (dir == 0 ? xyz1 : xyz2) + b * NPTS * 3;
    const float* dbase = (dir == 0 ? xyz2 : xyz1) + b * NPTS * 3 + csp * COLS * 3;

    // ---- two A fragments per wave (row-blocks of 32) ----
    h8 af[2];
#pragma unroll
    for (int rbi = 0; rbi < 2; ++rbi) {
        const int row = rb * RPB + wv * RPW + rbi * 32 + (lane & 31);
        float x = qbase[row * 3 + 0], y = qbase[row * 3 + 1], z2 = qbase[row * 3 + 2];
        float s = fmaf(x, x, fmaf(y, y, z2 * z2));
        _Float16 xh = (_Float16)x, yh = (_Float16)y, zh = (_Float16)z2;
        _Float16 xl = (_Float16)(x - (float)xh);
        _Float16 yl = (_Float16)(y - (float)yh);
        _Float16 zl = (_Float16)(z2 - (float)zh);
        _Float16 sh = (_Float16)s;
        _Float16 sl = (_Float16)(s - (float)sh);
        _Float16 one = (_Float16)1.0f, zero = (_Float16)0.0f;
        af[rbi] = (lane < 32) ? h8{xh, yh, zh, xh, yh, zh, xl, yl}
                              : h8{zl, sh, sl, one, one, zero, zero, zero};
    }

    const f32x16 Z = {};
    float rm[2][16];
#pragma unroll
    for (int rbi = 0; rbi < 2; ++rbi)
#pragma unroll
        for (int r = 0; r < 16; ++r) rm[rbi][r] = 3.0e38f;

    const int loff = ((lane >> 5) << 8) + (lane & 31) * 8;   // halfs

    // ---- staging: one col per thread per chunk (CHUNK == TPB) ----
    float vx, vy, vz;
    auto stage_load = [&](int ch) {
        const float* p = dbase + (ch * CHUNK + tid) * 3;
        vx = p[0]; vy = p[1]; vz = p[2];
    };
    auto stage_write = [&](int buf) {
        float s = fmaf(vx, vx, fmaf(vy, vy, vz * vz));
        _Float16 xh = (_Float16)vx, yh = (_Float16)vy, zh = (_Float16)vz;
        _Float16 m2xh = (_Float16)(-2.0f) * xh;
        _Float16 m2yh = (_Float16)(-2.0f) * yh;
        _Float16 m2zh = (_Float16)(-2.0f) * zh;
        _Float16 m2xl = (_Float16)(-2.0f * (vx - (float)xh));
        _Float16 m2yl = (_Float16)(-2.0f * (vy - (float)yh));
        _Float16 m2zl = (_Float16)(-2.0f * (vz - (float)zh));
        _Float16 sh = (_Float16)s;
        _Float16 sl = (_Float16)(s - (float)sh);
        _Float16 one = (_Float16)1.0f, zero = (_Float16)0.0f;
        int off = (tid >> 5) * 512 + (tid & 31) * 8;
        *(h8*)&sb[buf][off]       = h8{m2xh, m2yh, m2zh, m2xl, m2yl, m2zl, m2xh, m2yh};
        *(h8*)&sb[buf][off + 256] = h8{m2zh, one, one, sh, sl, zero, zero, zero};
    };

    auto sweep = [&](int buf) {
        const _Float16* base = &sb[buf][0];
#pragma unroll 1
        for (int t = 0; t < CHUNK / 32; t += 2) {
            h8 b0 = *(const h8*)(base + t * 512 + loff);
            h8 b1 = *(const h8*)(base + (t + 1) * 512 + loff);
#pragma unroll
            for (int rbi = 0; rbi < 2; ++rbi) {
                f32x16 a0 = __builtin_amdgcn_mfma_f32_32x32x16_f16(af[rbi], b0, Z, 0, 0, 0);
                f32x16 a1 = __builtin_amdgcn_mfma_f32_32x32x16_f16(af[rbi], b1, Z, 0, 0, 0);
#pragma unroll
                for (int r = 0; r < 16; ++r)
                    rm[rbi][r] = fminf(fminf(a0[r], a1[r]), rm[rbi][r]);  // v_min3_f32
            }
        }
    };

    stage_load(0);
    stage_write(0);
    __syncthreads();
#pragma unroll 1
    for (int ch = 0; ch < NCHUNK; ++ch) {
        int buf = ch & 1;
        if (ch + 1 < NCHUNK) stage_load(ch + 1);
        sweep(buf);
        if (ch + 1 < NCHUNK) stage_write(buf ^ 1);
        __syncthreads();
    }

    // ---- reduce over 32 col-lanes (butterfly within each half) ----
#pragma unroll
    for (int rbi = 0; rbi < 2; ++rbi)
#pragma unroll
        for (int r = 0; r < 16; ++r) {
            float m = rm[rbi][r];
            m = fminf(m, __shfl_xor(m, 1));
            m = fminf(m, __shfl_xor(m, 2));
            m = fminf(m, __shfl_xor(m, 4));
            m = fminf(m, __shfl_xor(m, 8));
            m = fminf(m, __shfl_xor(m, 16));
            rm[rbi][r] = m;
        }
    // ---- combine across col-splits via int atomicMin (values >= 0) ----
    if ((lane & 31) == 0) {
        const int half = lane >> 5;
        int* o = (int*)out + dir * (BB * NPTS) + b * NPTS + rb * RPB + wv * RPW;
#pragma unroll
        for (int rbi = 0; rbi < 2; ++rbi)
#pragma unroll
            for (int r = 0; r < 16; ++r) {
                int rr = (r & 3) + 8 * (r >> 2) + 4 * half;   // C/D row map (m74/m101)
                float val = fmaxf(rm[rbi][r], 0.0f);
                atomicMin(o + rbi * 32 + rr, __float_as_int(val));
            }
    }
}

extern "C" void kernel_launch(void* const* d_in, const int* in_sizes, int n_in,
                              void* d_out, int out_size, void* d_ws, size_t ws_size,
                              hipStream_t stream) {
    const float* xyz1 = (const float*)d_in[0];
    const float* xyz2 = (const float*)d_in[1];
    float* out = (float*)d_out;

    // init output to +big (harness poisons d_out; must rewrite every call)
    hipLaunchKernelGGL(chamfer_init_out, dim3(2 * BB * NPTS / 256), dim3(256), 0, stream, out);

    dim3 grid(NPTS / RPB, BB, 2 * CSPLIT);   // 16 x 16 x 4 = 1024 blocks
    hipLaunchKernelGGL(chamfer_mfma, grid, dim3(TPB), 0, stream, xyz1, xyz2, out);
}